// Round 8
// baseline (19.667 us; speedup 1.0000x reference)
//
#include <hip/hip_runtime.h>
#include <math.h>

#define TOPK 50
#define NCH 225
#define NT 1024
#define NW 16
#define MAXIT 7             // ceil(25600 / 4096)
#define CAP 512
#define NBINS 4096
#define BPT 4               // bins per thread (4096 / 1024)
#define PADC 5              // padded chunk stride (coprime with 32 banks)

// monotone float->uint key: preserves ordering, larger float -> larger key
__device__ __forceinline__ unsigned int f2key(float f) {
    unsigned int u = __float_as_uint(f);
    return (u & 0x80000000u) ? ~u : (u | 0x80000000u);
}
__device__ __forceinline__ float key2f(unsigned int k) {
    unsigned int u = (k & 0x80000000u) ? (k ^ 0x80000000u) : ~k;
    return __uint_as_float(u);
}
__device__ __forceinline__ int pbin(unsigned int bin) {
    return (int)((bin >> 2) * PADC + (bin & 3u));
}
__device__ __forceinline__ float sigm(float x) {
    return 1.0f / (1.0f + expf(-x));
}

struct Args {
    const float* conf[3];
    const float* obj[3];
    const float* act[3];
    const float* rel[3];
    const float* intp[3];
    const float* reg[3];
    float* out;
};

__global__ __launch_bounds__(NT)
void yowo_fused_kernel(Args a) {
    __shared__ unsigned int s_hist[NT * PADC];   // 20 KB
    __shared__ unsigned int s_w[NW];
    __shared__ unsigned int s_woff[NW];
    __shared__ unsigned int s_ck[CAP];
    __shared__ unsigned int s_ci[CAP];
    __shared__ unsigned int s_selKey[TOPK];
    __shared__ unsigned int s_selIdx[TOPK];
    __shared__ unsigned int s_cnt;
    __shared__ unsigned int s_bin, s_cntGe;
    __shared__ unsigned long long s_wred[NW];
    __shared__ unsigned long long s_prev;

    const int tid  = threadIdx.x;
    const int wid  = tid >> 6;
    const int lane = tid & 63;
    const int lvl  = blockIdx.x >> 5;
    const int b    = blockIdx.x & 31;
    const int M    = (lvl == 0) ? 25600 : (lvl == 1) ? 6400 : 1600;
    const int stride = 8 << lvl;
    const int n    = 1280 / stride;
    // probe thresholds: expected candidate count ~126/89/88 for N(0,1) logits;
    // any miss falls back to the exact histogram path below.
    const float Tf = (lvl == 0) ? 2.58f : (lvl == 1) ? 2.2f : 1.6f;
    const unsigned int Tkey = f2key(Tf);
    const float* confp = a.conf[lvl] + (size_t)b * M;

    // ---- Phase 1: load conf once (keys to registers); count keys > Tkey ----
    uint4 kk[MAXIT];
    int lc = 0;
    #pragma unroll
    for (int it = 0; it < MAXIT; ++it) {
        const int m = tid * 4 + it * (NT * 4);
        if (m < M) {
            float4 c4 = *(const float4*)(confp + m);
            uint4 k4 = make_uint4(f2key(c4.x), f2key(c4.y), f2key(c4.z), f2key(c4.w));
            kk[it] = k4;
            lc += (k4.x > Tkey) + (k4.y > Tkey) + (k4.z > Tkey) + (k4.w > Tkey);
        } else {
            kk[it] = make_uint4(0u, 0u, 0u, 0u);
        }
    }
    int c = lc;
    #pragma unroll
    for (int off = 32; off > 0; off >>= 1) c += __shfl_xor(c, off, 64);
    if (lane == 0) s_w[wid] = (unsigned int)c;
    __syncthreads();
    unsigned int total = 0u;
    #pragma unroll
    for (int j = 0; j < NW; ++j) total += s_w[j];

    unsigned int thrU = 0u;
    bool ok;
    if (total >= TOPK && total <= CAP) {
        thrU = Tkey + 1u;            // k > Tkey  <=>  k >= Tkey+1 (uint)
        ok = true;
    } else {
        // ---- exact fallback: 12-bit histogram select ----
        __syncthreads();
        {
            const int zb = tid * PADC;
            #pragma unroll
            for (int j = 0; j < PADC; ++j) s_hist[zb + j] = 0u;
        }
        __syncthreads();
        #pragma unroll
        for (int it = 0; it < MAXIT; ++it) {
            const int m = tid * 4 + it * (NT * 4);
            if (m < M) {
                const uint4 k4 = kk[it];
                atomicAdd(&s_hist[pbin(k4.x >> 20)], 1u);
                atomicAdd(&s_hist[pbin(k4.y >> 20)], 1u);
                atomicAdd(&s_hist[pbin(k4.z >> 20)], 1u);
                atomicAdd(&s_hist[pbin(k4.w >> 20)], 1u);
            }
        }
        __syncthreads();
        const int pb = tid * PADC;
        unsigned int ct = 0u;
        #pragma unroll
        for (int j = 0; j < BPT; ++j) ct += s_hist[pb + j];
        unsigned int sfx = ct;
        #pragma unroll
        for (int off = 1; off < 64; off <<= 1) {
            unsigned int v = __shfl_down(sfx, off, 64);
            if (lane + off < 64) sfx += v;
        }
        if (lane == 0) s_w[wid] = sfx;
        __syncthreads();
        if (tid < NW) {
            unsigned int o = 0u;
            for (int j = tid + 1; j < NW; ++j) o += s_w[j];
            s_woff[tid] = o;
        }
        __syncthreads();
        const unsigned int S_incl = sfx + s_woff[wid];
        const unsigned int right  = S_incl - ct;
        if (right < TOPK && S_incl >= TOPK) {
            unsigned int cge = right;
            #pragma unroll
            for (int j = BPT - 1; j >= 0; --j) {
                cge += s_hist[pb + j];
                if (cge >= TOPK) {
                    s_bin = (unsigned int)(tid * BPT + j);
                    s_cntGe = cge;
                    break;
                }
            }
        }
        __syncthreads();
        if (s_cntGe <= CAP) { thrU = s_bin << 20; ok = true; }
        else ok = false;
    }

    if (ok) {
        // ---- compact candidates (register-held keys) + rank-sort ----
        __syncthreads();
        if (tid == 0) s_cnt = 0u;
        __syncthreads();
        #pragma unroll
        for (int it = 0; it < MAXIT; ++it) {
            const int m = tid * 4 + it * (NT * 4);
            if (m < M) {
                const uint4 k4 = kk[it];
                #pragma unroll
                for (int j = 0; j < 4; ++j) {
                    const unsigned int k = (j == 0) ? k4.x : (j == 1) ? k4.y
                                         : (j == 2) ? k4.z : k4.w;
                    if (k >= thrU) {
                        unsigned int pos = atomicAdd(&s_cnt, 1u);
                        if (pos < CAP) {
                            s_ck[pos] = k;
                            s_ci[pos] = (unsigned int)(m + j);
                        }
                    }
                }
            }
        }
        __syncthreads();
        const unsigned int cnt = s_cnt;
        if (tid < (int)cnt) {
            const unsigned long long p =
                ((unsigned long long)s_ck[tid] << 32) | (unsigned int)(~s_ci[tid]);
            int rank = 0;
            for (unsigned int j = 0; j < cnt; ++j) {
                const unsigned long long q =
                    ((unsigned long long)s_ck[j] << 32) | (unsigned int)(~s_ci[j]);
                rank += (q > p) ? 1 : 0;
            }
            if (rank < TOPK) { s_selKey[rank] = s_ck[tid]; s_selIdx[rank] = s_ci[tid]; }
        }
        __syncthreads();
    } else {
        // ---- ultra fallback (massive key ties; never expected): 50 max passes ----
        unsigned long long prev = 0xFFFFFFFFFFFFFFFFull;
        for (int i = 0; i < TOPK; ++i) {
            unsigned long long p = 0ull;
            #pragma unroll
            for (int it = 0; it < MAXIT; ++it) {
                const int m = tid * 4 + it * (NT * 4);
                if (m < M) {
                    const uint4 k4 = kk[it];
                    #pragma unroll
                    for (int j = 0; j < 4; ++j) {
                        const unsigned int k = (j == 0) ? k4.x : (j == 1) ? k4.y
                                             : (j == 2) ? k4.z : k4.w;
                        const unsigned long long pk =
                            ((unsigned long long)k << 32) |
                            (unsigned int)(~(unsigned int)(m + j));
                        if (pk < prev && pk > p) p = pk;
                    }
                }
            }
            #pragma unroll
            for (int off = 32; off > 0; off >>= 1) {
                unsigned long long q = __shfl_xor(p, off, 64);
                if (q > p) p = q;
            }
            if (lane == 0) s_wred[wid] = p;
            __syncthreads();
            if (tid == 0) {
                unsigned long long w = s_wred[0];
                #pragma unroll
                for (int j = 1; j < NW; ++j) if (s_wred[j] > w) w = s_wred[j];
                s_prev = w;
                s_selKey[i] = (unsigned int)(w >> 32);
                s_selIdx[i] = ~(unsigned int)w;
            }
            __syncthreads();
            prev = s_prev;
            __syncthreads();
        }
        __syncthreads();
    }

    // ---- Phase 2: epilogue. Wave w owns rows {w, w+16, w+32, w+48} ----
    // Batched: issue ALL row gathers into statically-indexed registers first
    // (one latency round), then compute + store.
    const float* objp = a.obj[lvl];
    const float* actp = a.act[lvl];
    const float* relp = a.rel[lvl];
    const float* intp = a.intp[lvl];
    const float* regp = a.reg[lvl];

    float ov[4], a0[4], a1[4], a2[4], rv[4], iv[4];
    float4 rg[4];
    unsigned int gidx[4];

    #pragma unroll
    for (int s = 0; s < 4; ++s) {
        const int row = wid + 16 * s;
        const bool v = (row < TOPK);
        const unsigned int idx = v ? s_selIdx[row] : 0u;
        gidx[s] = idx;
        const size_t rb = (size_t)b * M + idx;
        ov[s] = (v && lane < 36) ? objp[rb * 36 + lane] : 0.0f;
        a0[s] = v ? actp[rb * 157 + lane] : 0.0f;
        a1[s] = (v && lane + 64 < 157) ? actp[rb * 157 + lane + 64] : 0.0f;
        a2[s] = (v && lane + 128 < 157) ? actp[rb * 157 + lane + 128] : 0.0f;
        rv[s] = (v && lane < 26) ? relp[rb * 26 + lane] : 0.0f;
        iv[s] = (v && lane == 0) ? intp[rb] : 0.0f;
        rg[s] = (v && lane == 0) ? *(const float4*)(regp + rb * 4)
                                 : make_float4(0.f, 0.f, 0.f, 0.f);
    }

    #pragma unroll
    for (int s = 0; s < 4; ++s) {
        const int row = wid + 16 * s;
        if (row < TOPK) {
            const unsigned int idx = gidx[s];
            const float logit = key2f(s_selKey[row]);
            const float sc   = sigm(logit);
            const float keep = (sc > 0.05f) ? 1.0f : 0.0f;
            float* orow = a.out + ((size_t)b * 150 + (size_t)lvl * TOPK + row) * NCH;

            // obj softmax over 36 classes (lanes>=36 contribute 0)
            float e = (lane < 36) ? expf(ov[s]) : 0.0f;
            float sum = e;
            #pragma unroll
            for (int off = 32; off > 0; off >>= 1) sum += __shfl_xor(sum, off, 64);
            if (lane < 36) orow[6 + lane] = keep * (e / sum);

            // act sigmoid (157)
            orow[42 + lane] = keep * sigm(a0[s]);
            if (lane + 64 < 157)  orow[42 + lane + 64]  = keep * sigm(a1[s]);
            if (lane + 128 < 157) orow[42 + lane + 128] = keep * sigm(a2[s]);
            // rel sigmoid (26)
            if (lane < 26) orow[199 + lane] = keep * sigm(rv[s]);
            // conf, inter, box
            if (lane == 0) {
                orow[4] = keep * sc;
                orow[5] = keep * sigm(iv[s]);
                const int yy = (int)idx / n;
                const int xx = (int)idx % n;
                const float fs = (float)stride;
                const float cx = (xx + 0.5f) * fs + rg[s].x * fs;
                const float cy = (yy + 0.5f) * fs + rg[s].y * fs;
                const float w2 = 0.5f * expf(rg[s].z) * fs;
                const float h2 = 0.5f * expf(rg[s].w) * fs;
                orow[0] = keep * (cx - w2);
                orow[1] = keep * (cy - h2);
                orow[2] = keep * (cx + w2);
                orow[3] = keep * (cy + h2);
            }
        }
    }
}

extern "C" void kernel_launch(void* const* d_in, const int* in_sizes, int n_in,
                              void* d_out, int out_size, void* d_ws, size_t ws_size,
                              hipStream_t stream) {
    (void)in_sizes; (void)n_in; (void)out_size; (void)d_ws; (void)ws_size;
    Args a;
    for (int l = 0; l < 3; ++l) {
        a.conf[l] = (const float*)d_in[l * 6 + 0];
        a.obj[l]  = (const float*)d_in[l * 6 + 1];
        a.act[l]  = (const float*)d_in[l * 6 + 2];
        a.rel[l]  = (const float*)d_in[l * 6 + 3];
        a.intp[l] = (const float*)d_in[l * 6 + 4];
        a.reg[l]  = (const float*)d_in[l * 6 + 5];
    }
    a.out = (float*)d_out;
    hipLaunchKernelGGL(yowo_fused_kernel, dim3(96), dim3(NT), 0, stream, a);
}

// Round 9
// 19.194 us; speedup vs baseline: 1.0246x; 1.0246x over previous
//
#include <hip/hip_runtime.h>
#include <math.h>

#define TOPK 50
#define NCH 225
#define NT 1024
#define NW 16
#define MAXIT 7             // ceil(25600 / 4096)
#define CAP 512
#define NBINS 4096
#define BPT 4               // bins per thread (4096 / 1024)
#define PADC 5              // padded chunk stride (coprime with 32 banks)

// monotone float->uint key: preserves ordering, larger float -> larger key
__device__ __forceinline__ unsigned int f2key(float f) {
    unsigned int u = __float_as_uint(f);
    return (u & 0x80000000u) ? ~u : (u | 0x80000000u);
}
__device__ __forceinline__ float key2f(unsigned int k) {
    unsigned int u = (k & 0x80000000u) ? (k ^ 0x80000000u) : ~k;
    return __uint_as_float(u);
}
__device__ __forceinline__ int pbin(unsigned int bin) {
    return (int)((bin >> 2) * PADC + (bin & 3u));
}

struct ArgsA { const float* conf[3]; uint2* sel; };

struct ArgsB {
    const float* obj[3];
    const float* act[3];
    const float* rel[3];
    const float* intp[3];
    const float* reg[3];
    const uint2* sel;
    float* out;
};

// ---- Kernel A: exact top-50 per (lvl, batch); threshold-probe fast path ----
__global__ __launch_bounds__(NT)
void yowo_select_kernel(ArgsA a) {
    __shared__ unsigned int s_hist[NT * PADC];   // 20 KB
    __shared__ unsigned int s_w[NW];
    __shared__ unsigned int s_woff[NW];
    __shared__ unsigned int s_ck[CAP];
    __shared__ unsigned int s_ci[CAP];
    __shared__ unsigned int s_selKey[TOPK];
    __shared__ unsigned int s_selIdx[TOPK];
    __shared__ unsigned int s_cnt;
    __shared__ unsigned int s_total;
    __shared__ unsigned int s_bin, s_cntGe;
    __shared__ unsigned long long s_wred[NW];
    __shared__ unsigned long long s_prev;

    const int tid  = threadIdx.x;
    const int wid  = tid >> 6;
    const int lane = tid & 63;
    const int lvl  = blockIdx.x >> 5;
    const int b    = blockIdx.x & 31;
    const int M    = (lvl == 0) ? 25600 : (lvl == 1) ? 6400 : 1600;
    // probe thresholds: expected candidate count ~126/89/88 for N(0,1) logits;
    // any miss falls back to the exact histogram path below.
    const float Tf = (lvl == 0) ? 2.58f : (lvl == 1) ? 2.2f : 1.6f;
    const unsigned int Tkey = f2key(Tf);
    const float* confp = a.conf[lvl] + (size_t)b * M;

    // ---- load conf once; keys to registers; count keys > Tkey ----
    uint4 kk[MAXIT];
    int lc = 0;
    #pragma unroll
    for (int it = 0; it < MAXIT; ++it) {
        const int m = tid * 4 + it * (NT * 4);
        if (m < M) {
            float4 c4 = *(const float4*)(confp + m);
            uint4 k4 = make_uint4(f2key(c4.x), f2key(c4.y), f2key(c4.z), f2key(c4.w));
            kk[it] = k4;
            lc += (k4.x > Tkey) + (k4.y > Tkey) + (k4.z > Tkey) + (k4.w > Tkey);
        } else {
            kk[it] = make_uint4(0u, 0u, 0u, 0u);
        }
    }
    // block-wide count
    int c = lc;
    #pragma unroll
    for (int off = 32; off > 0; off >>= 1) c += __shfl_xor(c, off, 64);
    if (lane == 0) s_w[wid] = (unsigned int)c;
    __syncthreads();
    if (tid == 0) {
        unsigned int t = 0u;
        #pragma unroll
        for (int j = 0; j < NW; ++j) t += s_w[j];
        s_total = t;
    }
    __syncthreads();
    const unsigned int total = s_total;

    unsigned int thrU = 0u;
    bool ok;
    if (total >= TOPK && total <= CAP) {
        thrU = Tkey + 1u;            // k > Tkey  <=>  k >= Tkey+1
        ok = true;
    } else {
        // ---- exact fallback: 12-bit histogram select ----
        {
            const int zb = tid * PADC;
            #pragma unroll
            for (int j = 0; j < PADC; ++j) s_hist[zb + j] = 0u;
        }
        __syncthreads();
        #pragma unroll
        for (int it = 0; it < MAXIT; ++it) {
            const int m = tid * 4 + it * (NT * 4);
            if (m < M) {
                const uint4 k4 = kk[it];
                atomicAdd(&s_hist[pbin(k4.x >> 20)], 1u);
                atomicAdd(&s_hist[pbin(k4.y >> 20)], 1u);
                atomicAdd(&s_hist[pbin(k4.z >> 20)], 1u);
                atomicAdd(&s_hist[pbin(k4.w >> 20)], 1u);
            }
        }
        __syncthreads();
        const int pb = tid * PADC;
        unsigned int ct = 0u;
        #pragma unroll
        for (int j = 0; j < BPT; ++j) ct += s_hist[pb + j];
        unsigned int sfx = ct;
        #pragma unroll
        for (int off = 1; off < 64; off <<= 1) {
            unsigned int v = __shfl_down(sfx, off, 64);
            if (lane + off < 64) sfx += v;
        }
        if (lane == 0) s_w[wid] = sfx;
        __syncthreads();
        if (tid < NW) {
            unsigned int o = 0u;
            for (int j = tid + 1; j < NW; ++j) o += s_w[j];
            s_woff[tid] = o;
        }
        __syncthreads();
        const unsigned int S_incl = sfx + s_woff[wid];
        const unsigned int right  = S_incl - ct;
        if (right < TOPK && S_incl >= TOPK) {
            unsigned int cge = right;
            #pragma unroll
            for (int j = BPT - 1; j >= 0; --j) {
                cge += s_hist[pb + j];
                if (cge >= TOPK) {
                    s_bin = (unsigned int)(tid * BPT + j);
                    s_cntGe = cge;
                    break;
                }
            }
        }
        __syncthreads();
        if (s_cntGe <= CAP) { thrU = s_bin << 20; ok = true; }
        else ok = false;
    }

    if (ok) {
        // ---- compact candidates (register-held keys) + rank-sort ----
        __syncthreads();
        if (tid == 0) s_cnt = 0u;
        __syncthreads();
        #pragma unroll
        for (int it = 0; it < MAXIT; ++it) {
            const int m = tid * 4 + it * (NT * 4);
            if (m < M) {
                const uint4 k4 = kk[it];
                #pragma unroll
                for (int j = 0; j < 4; ++j) {
                    const unsigned int k = (j == 0) ? k4.x : (j == 1) ? k4.y
                                         : (j == 2) ? k4.z : k4.w;
                    if (k >= thrU) {
                        unsigned int pos = atomicAdd(&s_cnt, 1u);
                        if (pos < CAP) {
                            s_ck[pos] = k;
                            s_ci[pos] = (unsigned int)(m + j);
                        }
                    }
                }
            }
        }
        __syncthreads();
        const unsigned int cnt = s_cnt;
        if (tid < (int)cnt) {
            const unsigned long long p =
                ((unsigned long long)s_ck[tid] << 32) | (unsigned int)(~s_ci[tid]);
            int rank = 0;
            for (unsigned int j = 0; j < cnt; ++j) {
                const unsigned long long q =
                    ((unsigned long long)s_ck[j] << 32) | (unsigned int)(~s_ci[j]);
                rank += (q > p) ? 1 : 0;
            }
            if (rank < TOPK) { s_selKey[rank] = s_ck[tid]; s_selIdx[rank] = s_ci[tid]; }
        }
        __syncthreads();
    } else {
        // ---- ultra fallback (massive key ties; never expected): 50 max passes ----
        unsigned long long prev = 0xFFFFFFFFFFFFFFFFull;
        for (int i = 0; i < TOPK; ++i) {
            unsigned long long p = 0ull;
            #pragma unroll
            for (int it = 0; it < MAXIT; ++it) {
                const int m = tid * 4 + it * (NT * 4);
                if (m < M) {
                    const uint4 k4 = kk[it];
                    #pragma unroll
                    for (int j = 0; j < 4; ++j) {
                        const unsigned int k = (j == 0) ? k4.x : (j == 1) ? k4.y
                                             : (j == 2) ? k4.z : k4.w;
                        const unsigned long long pk =
                            ((unsigned long long)k << 32) |
                            (unsigned int)(~(unsigned int)(m + j));
                        if (pk < prev && pk > p) p = pk;
                    }
                }
            }
            #pragma unroll
            for (int off = 32; off > 0; off >>= 1) {
                unsigned long long q = __shfl_xor(p, off, 64);
                if (q > p) p = q;
            }
            if (lane == 0) s_wred[wid] = p;
            __syncthreads();
            if (tid == 0) {
                unsigned long long w = s_wred[0];
                #pragma unroll
                for (int j = 1; j < NW; ++j) if (s_wred[j] > w) w = s_wred[j];
                s_prev = w;
                s_selKey[i] = (unsigned int)(w >> 32);
                s_selIdx[i] = ~(unsigned int)w;
            }
            __syncthreads();
            prev = s_prev;
            __syncthreads();
        }
    }

    if (tid < TOPK)
        a.sel[(size_t)blockIdx.x * TOPK + tid] =
            make_uint2(s_selKey[tid], s_selIdx[tid]);
}

// ---- Kernel B: pure gather/epilogue, one row per wave ----
__global__ __launch_bounds__(NT)
void yowo_out_kernel(ArgsB a) {
    __shared__ unsigned int s_k[TOPK];
    __shared__ unsigned int s_i[TOPK];

    const int tid  = threadIdx.x;
    const int wid  = tid >> 6;
    const int lane = tid & 63;
    const int grp  = blockIdx.x >> 2;   // 0..95 = lvl*32 + b
    const int sub  = blockIdx.x & 3;
    const int lvl  = grp >> 5;
    const int b    = grp & 31;

    const int M      = (lvl == 0) ? 25600 : (lvl == 1) ? 6400 : 1600;
    const int stride = 8 << lvl;
    const int n      = 1280 / stride;

    if (tid < TOPK) {
        uint2 e = a.sel[(size_t)grp * TOPK + tid];
        s_k[tid] = e.x;
        s_i[tid] = e.y;
    }
    __syncthreads();

    const int k = sub + 4 * wid;
    if (k < TOPK) {
        const unsigned int idx = s_i[k];
        const float logit = key2f(s_k[k]);
        const float sc   = 1.0f / (1.0f + expf(-logit));
        const float keep = (sc > 0.05f) ? 1.0f : 0.0f;

        float* orow = a.out + ((size_t)b * 150 + (size_t)lvl * TOPK + k) * NCH;
        const size_t rbase = (size_t)b * M + idx;

        // obj softmax over 36 classes (full-wave shuffle sum; lanes>=36 add 0)
        float e = 0.0f;
        if (lane < 36) e = expf(a.obj[lvl][rbase * 36 + lane]);
        float s = e;
        #pragma unroll
        for (int off = 32; off > 0; off >>= 1) s += __shfl_xor(s, off, 64);
        if (lane < 36) orow[6 + lane] = keep * (e / s);

        // act sigmoid (157)
        for (int cix = lane; cix < 157; cix += 64) {
            float x = a.act[lvl][rbase * 157 + cix];
            orow[42 + cix] = keep / (1.0f + expf(-x));
        }
        // rel sigmoid (26)
        if (lane < 26) {
            float x = a.rel[lvl][rbase * 26 + lane];
            orow[199 + lane] = keep / (1.0f + expf(-x));
        }
        // conf, inter, box
        if (lane == 0) {
            orow[4] = keep * sc;
            float xi = a.intp[lvl][rbase];
            orow[5] = keep / (1.0f + expf(-xi));
            const float r0 = a.reg[lvl][rbase * 4 + 0];
            const float r1 = a.reg[lvl][rbase * 4 + 1];
            const float r2 = a.reg[lvl][rbase * 4 + 2];
            const float r3 = a.reg[lvl][rbase * 4 + 3];
            const int yy = (int)idx / n;
            const int xx = (int)idx % n;
            const float fs = (float)stride;
            const float cx = (xx + 0.5f) * fs + r0 * fs;
            const float cy = (yy + 0.5f) * fs + r1 * fs;
            const float w2 = 0.5f * expf(r2) * fs;
            const float h2 = 0.5f * expf(r3) * fs;
            orow[0] = keep * (cx - w2);
            orow[1] = keep * (cy - h2);
            orow[2] = keep * (cx + w2);
            orow[3] = keep * (cy + h2);
        }
    }
}

extern "C" void kernel_launch(void* const* d_in, const int* in_sizes, int n_in,
                              void* d_out, int out_size, void* d_ws, size_t ws_size,
                              hipStream_t stream) {
    (void)in_sizes; (void)n_in; (void)out_size; (void)ws_size;
    uint2* sel = (uint2*)d_ws;            // 96*50*8 = 38400 B

    ArgsA aa;
    ArgsB ab;
    for (int l = 0; l < 3; ++l) {
        aa.conf[l] = (const float*)d_in[l * 6 + 0];
        ab.obj[l]  = (const float*)d_in[l * 6 + 1];
        ab.act[l]  = (const float*)d_in[l * 6 + 2];
        ab.rel[l]  = (const float*)d_in[l * 6 + 3];
        ab.intp[l] = (const float*)d_in[l * 6 + 4];
        ab.reg[l]  = (const float*)d_in[l * 6 + 5];
    }
    aa.sel = sel;
    ab.sel = sel;
    ab.out = (float*)d_out;

    hipLaunchKernelGGL(yowo_select_kernel, dim3(96), dim3(NT), 0, stream, aa);
    hipLaunchKernelGGL(yowo_out_kernel, dim3(384), dim3(NT), 0, stream, ab);
}